// Round 16
// baseline (159.860 us; speedup 1.0000x reference)
//
#include <hip/hip_runtime.h>
#include <math.h>

#define BB 16
#define NP 8192
#define NV 42
#define NF 80
#define FEAT 256
#define PPB 64           // points per block (mvc)
#define FH  40           // faces per half-wave
#define WJS 65           // padded LDS stride (65%32==1 -> transposed epilogue conflict-free)

__device__ __forceinline__ float rcp_f(float x)  { return __builtin_amdgcn_rcpf(x); }
__device__ __forceinline__ float rsq_f(float x)  { return __builtin_amdgcn_rsqf(x); }
__device__ __forceinline__ float sqrt_f(float x) { return __builtin_amdgcn_sqrtf(x); }

// theta = 2*asin(x), x in [0,1). Branchless, |err|~1e-5. (validated r2-r15)
__device__ __forceinline__ float theta_from_x(float x) {
  bool big = x > 0.5f;
  float z = big ? fmaf(-0.5f, x, 0.5f) : x * x;
  float s = big ? sqrt_f(z) : x;
  float P = fmaf(z, 0.022371875f, 0.030381944f);
  P = fmaf(z, P, 0.044642857f);
  P = fmaf(z, P, 0.075f);
  P = fmaf(z, P, 0.16666667f);
  float r = fmaf(s * z, P, s);
  return big ? fmaf(-4.f, r, 3.14159265358979f) : 2.f * r;
}

// cold path: runtime face recompute, inside-formula accumulate into private region
__device__ __attribute__((noinline)) void inside_face_rt(
    int f0, int f1, int f2, const float4* vpos,
    float qx, float qy, float qz, float* wjh)   // wjh = &wj[hf*NV*WJS + p]
{
  float4 v0 = vpos[f0], v1 = vpos[f1], v2 = vpos[f2];
  float a0x = v0.x - qx, a0y = v0.y - qy, a0z = v0.z - qz;
  float a1x = v1.x - qx, a1y = v1.y - qy, a1z = v1.z - qz;
  float a2x = v2.x - qx, a2y = v2.y - qy, a2z = v2.z - qz;
  float ss0 = fmaf(a0x, a0x, fmaf(a0y, a0y, a0z * a0z));
  float ss1 = fmaf(a1x, a1x, fmaf(a1y, a1y, a1z * a1z));
  float ss2 = fmaf(a2x, a2x, fmaf(a2y, a2y, a2z * a2z));
  float i0 = rsq_f(ss0), i1 = rsq_f(ss1), i2 = rsq_f(ss2);
  float d0 = ss0 * i0, d1 = ss1 * i1, d2 = ss2 * i2;
  float u0x = a0x * i0, u0y = a0y * i0, u0z = a0z * i0;
  float u1x = a1x * i1, u1y = a1y * i1, u1z = a1z * i1;
  float u2x = a2x * i2, u2y = a2y * i2, u2z = a2z * i2;
  float ex = u1x - u2x, ey = u1y - u2y, ez = u1z - u2z;
  float x0 = 0.5f * sqrt_f(fmaf(ex, ex, fmaf(ey, ey, ez * ez)));
  ex = u2x - u0x; ey = u2y - u0y; ez = u2z - u0z;
  float x1 = 0.5f * sqrt_f(fmaf(ex, ex, fmaf(ey, ey, ez * ez)));
  ex = u0x - u1x; ey = u0y - u1y; ez = u0z - u1z;
  float x2 = 0.5f * sqrt_f(fmaf(ex, ex, fmaf(ey, ey, ez * ez)));
  if (x0 >= 1.f) x0 = 0.99999f;
  if (x1 >= 1.f) x1 = 0.99999f;
  if (x2 >= 1.f) x2 = 0.99999f;
  float th0 = theta_from_x(x0), th1 = theta_from_x(x1), th2 = theta_from_x(x2);
  float hh = 0.5f * ((th0 + th1) + th2);
  if (3.14159265358979f - hh < 1e-4f) {
    float cx0 = sqrt_f(fmaxf(fmaf(-x0, x0, 1.f), 0.f));
    float cx1 = sqrt_f(fmaxf(fmaf(-x1, x1, 1.f), 0.f));
    float cx2 = sqrt_f(fmaxf(fmaf(-x2, x2, 1.f), 0.f));
    wjh[f0 * WJS] += (2.f * (x0 * cx0) * d2) * d1;
    wjh[f1 * WJS] += (2.f * (x1 * cx1) * d0) * d2;
    wjh[f2 * WJS] += (2.f * (x2 * cx2) * d1) * d0;
  }
}

// ---------------- Kernel D: MVC weights + deformed ----------------
// 128 threads: wave0 = faces [0,40) of point p=lane, wave1 = faces [40,80).
// Software-pipelined accumulator: next face's vpos prefetched early, next
// face's wj accumulators read AFTER this face's writes (in-order LDS per
// wave preserves the shared-vertex hazard), consumed a full face later.
__global__ __launch_bounds__(128) void mvc_kernel(
    const float* __restrict__ src,      // (B,3,N)
    const float* __restrict__ cage_t,   // (B,42,3)
    const float* __restrict__ ncage_t,  // (B,42,3)
    const int* __restrict__ faces,      // (80,3)
    float* __restrict__ out_def,        // (B,3,N)
    float* __restrict__ out_w)          // (B,N,42)
{
  __shared__ float4 vpos[NV];
  __shared__ float4 npos[NV];
  __shared__ int fidp[NF];
  __shared__ float wj[2 * NV * WJS];
  __shared__ unsigned long long closeM1[PPB];
  __shared__ unsigned char insideF[2][PPB];

  const float PI_F = 3.14159265358979323846f;
  int tid = threadIdx.x;
  int p   = tid & (PPB - 1);
  int hf  = tid >> 6;
  int b    = blockIdx.x / (NP / PPB);
  int pblk = blockIdx.x % (NP / PPB);
  int gp   = pblk * PPB + p;

  if (tid < NV) {
    const float* cp = cage_t + (size_t)b * NV * 3 + tid * 3;
    vpos[tid] = make_float4(cp[0], cp[1], cp[2], 0.f);
    const float* np_ = ncage_t + (size_t)b * NV * 3 + tid * 3;
    npos[tid] = make_float4(np_[0], np_[1], np_[2], 0.f);
  }
  if (tid < NF) {
    int f0 = faces[3 * tid], f1 = faces[3 * tid + 1], f2 = faces[3 * tid + 2];
    fidp[tid] = f0 | (f1 << 6) | (f2 << 12);
  }
  for (int i = tid; i < 2 * NV * WJS; i += 128) wj[i] = 0.f;
  __syncthreads();

  float qx = src[(size_t)b * 3 * NP + gp];
  float qy = src[(size_t)b * 3 * NP + NP + gp];
  float qz = src[(size_t)b * 3 * NP + 2 * NP + gp];

  // close-mask hoist (r12-validated): per-vertex distance check covers the
  // reference's dj<1e-8 over all vertices. Both waves compute identical
  // masks; wave0 stores.
  {
    unsigned long long cl = 0ull;
    for (int c = 0; c < NV; c++) {
      float4 v = vpos[c];
      float ax = v.x - qx, ay = v.y - qy, az = v.z - qz;
      float ss = fmaf(ax, ax, fmaf(ay, ay, az * az));
      if (ss < 1e-16f) cl |= (1ull << c);   // d<1e-8 <=> ss<1e-16
    }
    if (hf == 0) closeM1[p] = cl;
  }

  int anyInside = 0;
  float* wjh = wj + hf * (NV * WJS) + p;

  // one face from preloaded vertex positions (r8-validated math)
  auto face_eval = [&](float4 v0, float4 v1, float4 v2,
                       float& w0, float& w1, float& w2) {
    float a0x = v0.x - qx, a0y = v0.y - qy, a0z = v0.z - qz;
    float a1x = v1.x - qx, a1y = v1.y - qy, a1z = v1.z - qz;
    float a2x = v2.x - qx, a2y = v2.y - qy, a2z = v2.z - qz;
    float ss0 = fmaf(a0x, a0x, fmaf(a0y, a0y, a0z * a0z));
    float ss1 = fmaf(a1x, a1x, fmaf(a1y, a1y, a1z * a1z));
    float ss2 = fmaf(a2x, a2x, fmaf(a2y, a2y, a2z * a2z));
    float i0 = rsq_f(ss0), i1 = rsq_f(ss1), i2 = rsq_f(ss2);
    float d0 = ss0 * i0, d1 = ss1 * i1, d2 = ss2 * i2;
    float u0x = a0x * i0, u0y = a0y * i0, u0z = a0z * i0;
    float u1x = a1x * i1, u1y = a1y * i1, u1z = a1z * i1;
    float u2x = a2x * i2, u2y = a2y * i2, u2z = a2z * i2;
    // chord half-lengths via EDGE SUBTRACTION (r7 lesson: never 1-u.u')
    float ex = u1x - u2x, ey = u1y - u2y, ez = u1z - u2z;
    float x0 = 0.5f * sqrt_f(fmaf(ex, ex, fmaf(ey, ey, ez * ez)));
    ex = u2x - u0x; ey = u2y - u0y; ez = u2z - u0z;
    float x1 = 0.5f * sqrt_f(fmaf(ex, ex, fmaf(ey, ey, ez * ez)));
    ex = u0x - u1x; ey = u0y - u1y; ez = u0z - u1z;
    float x2 = 0.5f * sqrt_f(fmaf(ex, ex, fmaf(ey, ey, ez * ez)));
    if (x0 >= 1.f) x0 = 0.99999f;     // reference clamp l>=2 -> 1.99998
    if (x1 >= 1.f) x1 = 0.99999f;
    if (x2 >= 1.f) x2 = 0.99999f;
    float cx0 = sqrt_f(fmaxf(fmaf(-x0, x0, 1.f), 0.f));
    float cx1 = sqrt_f(fmaxf(fmaf(-x1, x1, 1.f), 0.f));
    float cx2 = sqrt_f(fmaxf(fmaf(-x2, x2, 1.f), 0.f));
    float th0 = theta_from_x(x0);
    float th1 = theta_from_x(x1);
    float th2 = theta_from_x(x2);
    float hh = 0.5f * ((th0 + th1) + th2);
    if (PI_F - hh < 1e-4f) anyInside = 1;
    float t0 = x0 * cx0, t1 = x1 * cx1, t2 = x2 * cx2;
    float st0 = t0 + t0, st1 = t1 + t1, st2 = t2 + t2;   // sin(theta_i)
    float A1 = x0 * (cx1 * cx2);
    float A2 = x1 * (cx0 * cx2);
    float A3 = x2 * (cx0 * cx1);
    float A4 = x0 * (x1 * x2);
    float sh  = ((A1 + A2) + A3) - A4;     // sin(h)
    float sm0 = ((-A1 + A2) + A3) + A4;    // sin(h-th0)
    float sm1 = ((A1 - A2) + A3) + A4;
    float sm2 = ((A1 + A2) - A3) + A4;
    float twosh = sh + sh;
    float c0 = fmaf(twosh * sm0, rcp_f(st1 * st2), -1.f);
    float c1 = fmaf(twosh * sm1, rcp_f(st2 * st0), -1.f);
    float c2 = fmaf(twosh * sm2, rcp_f(st0 * st1), -1.f);
    c0 = fminf(fmaxf(c0, -0.99999f), 0.99999f);
    c1 = fminf(fmaxf(c1, -0.99999f), 0.99999f);
    c2 = fminf(fmaxf(c2, -0.99999f), 0.99999f);
    float det = u0x * fmaf(u1y, u2z, -(u1z * u2y))
              - u0y * fmaf(u1x, u2z, -(u1z * u2x))
              + u0z * fmaf(u1x, u2y, -(u1y * u2x));
    float sg = (det > 0.f) ? 1.f : ((det < 0.f) ? -1.f : 0.f);
    float sn0 = sg * sqrt_f(fmaf(-c0, c0, 1.f));
    float sn1 = sg * sqrt_f(fmaf(-c1, c1, 1.f));
    float sn2 = sg * sqrt_f(fmaf(-c2, c2, 1.f));
    w0 = fmaf(-c2, th1, fmaf(-c1, th2, th0)) * rcp_f((d0 * st1) * sn2);
    w1 = fmaf(-c0, th2, fmaf(-c2, th0, th1)) * rcp_f((d1 * st2) * sn0);
    w2 = fmaf(-c1, th0, fmaf(-c0, th1, th2)) * rcp_f((d2 * st0) * sn1);
  };

  // software-pipelined accumulate loop
  {
    int base = hf * FH;
    int pk = fidp[base];
    int g0 = pk & 63, g1 = (pk >> 6) & 63, g2 = pk >> 12;
    float4 fv0 = vpos[g0], fv1 = vpos[g1], fv2 = vpos[g2];
    float r0 = wjh[g0 * WJS], r1 = wjh[g1 * WJS], r2 = wjh[g2 * WJS];
    #pragma unroll 1
    for (int i = base; i < base + FH; i++) {
      // early prefetch of next face's indices + vertex positions
      int inx = (i + 1 < base + FH) ? i + 1 : i;   // clamped (last iter values unused)
      int pkn = fidp[inx];
      int n0 = pkn & 63, n1 = (pkn >> 6) & 63, n2 = pkn >> 12;
      float4 nv0 = vpos[n0], nv1 = vpos[n1], nv2 = vpos[n2];
      float w0, w1, w2;
      face_eval(fv0, fv1, fv2, w0, w1, w2);        // ~500 cycles of compute
      wjh[g0 * WJS] = r0 + w0;                     // write-back this face
      wjh[g1 * WJS] = r1 + w1;
      wjh[g2 * WJS] = r2 + w2;
      r0 = wjh[n0 * WJS];                          // read next AFTER writes
      r1 = wjh[n1 * WJS];                          // (shared-vertex hazard;
      r2 = wjh[n2 * WJS];                          //  in-order LDS per wave)
      g0 = n0; g1 = n1; g2 = n2;
      fv0 = nv0; fv1 = nv1; fv2 = nv2;
    }
  }

  insideF[hf][p] = (unsigned char)anyInside;
  __syncthreads();

  int mIn = insideF[0][p] | insideF[1][p];
  unsigned long long mCl = closeM1[p];

  if (mIn) {   // cold: exact `where(inside, ...)` semantics
    for (int c = 0; c < NV; c++) wjh[c * WJS] = 0.f;
    #pragma unroll 1
    for (int i = hf * FH; i < hf * FH + FH; i++) {
      int pk = fidp[i];
      inside_face_rt(pk & 63, (pk >> 6) & 63, pk >> 12, vpos, qx, qy, qz, wjh);
    }
  }
  __syncthreads();

  if (tid < PPB) {
    float sum = 0.f;
    for (int c = 0; c < NV; c++) {
      float w = wj[c * WJS + p] + wj[(NV + c) * WJS + p];
      if (mCl) w = ((mCl >> c) & 1ull) ? 1.f : 0.f;
      wj[c * WJS + p] = w;
      sum += w;
    }
    if (sum == 0.f) sum = 1.f;
    float inv = rcp_f(sum);
    float ax = 0.f, ay = 0.f, az = 0.f;
    for (int c = 0; c < NV; c++) {
      float w = wj[c * WJS + p] * inv;
      wj[c * WJS + p] = w;
      float4 n = npos[c];
      ax = fmaf(w, n.x, ax);
      ay = fmaf(w, n.y, ay);
      az = fmaf(w, n.z, az);
    }
    out_def[(size_t)b * 3 * NP + gp]          = ax;
    out_def[(size_t)b * 3 * NP + NP + gp]     = ay;
    out_def[(size_t)b * 3 * NP + 2 * NP + gp] = az;
  }
  __syncthreads();

  // coalesced weight write; stride 65 -> conflict-free transposed read
  float* wbase = out_w + ((size_t)b * NP + pblk * PPB) * NV;
  for (int idx = tid; idx < PPB * NV; idx += 128) {
    int pp = idx / NV;
    int c  = idx - pp * NV;
    wbase[idx] = wj[c * WJS + pp];
  }
}

// ---------------- shared split-K linear body (round-3 proven) ----------------
__device__ __forceinline__ void splitk_body(
    const float* in0, const float* in1,
    const float* W, const float* bias, float* out,
    int FI, int FO, int relu, int ox, int bb, int tid,
    float* sIn, float (*part)[64])
{
  for (int i = tid; i < FI; i += 256) {
    float v;
    if (in1) v = (i < FEAT) ? in0[(size_t)bb * FEAT + i]
                            : in1[(size_t)bb * FEAT + i - FEAT];
    else     v = in0[(size_t)bb * FI + i];
    sIn[i] = v;
  }
  __syncthreads();
  int o = ox * 64 + (tid & 63);
  int kk = tid >> 6;
  int seg = FI >> 2;
  float acc = 0.f;
  const float* wp = W + o;
  #pragma unroll 4
  for (int i = kk * seg; i < (kk + 1) * seg; i++)
    acc = fmaf(sIn[i], wp[(size_t)i * FO], acc);
  part[kk][tid & 63] = acc;
  __syncthreads();
  if (tid < 64) {
    float r = ((part[0][tid] + part[1][tid]) + (part[2][tid] + part[3][tid]))
              + bias[o];
    out[(size_t)bb * FO + o] = relu ? fmaxf(r, 0.f) : r;
  }
}

// ---------------- Kernel A: cage_opt (blocks<672) + L1 split-K (672..799) ----
__global__ __launch_bounds__(256) void cage_l1_kernel(
    const float* __restrict__ tmpl, const float* __restrict__ src,
    const float* __restrict__ sf, const float* __restrict__ tf,
    const float* __restrict__ W1, const float* __restrict__ b1,
    float* __restrict__ cage, float* __restrict__ h1)
{
  __shared__ float red[8];
  __shared__ float sIn[512];
  __shared__ float part[4][64];
  int tid = threadIdx.x;

  if (blockIdx.x < BB * NV) {
    int b = blockIdx.x / NV;
    int v = blockIdx.x % NV;
    const float* sp = src + (size_t)b * 3 * NP;
    float cx = tmpl[v], cy = tmpl[NV + v], cz = tmpl[2 * NV + v];
    int k = 0;
    while (true) {
      float m = 3.4e38f;
      for (int i = tid; i < NP; i += 256) {
        float dx = __fsub_rn(cx, sp[i]);
        float dy = __fsub_rn(cy, sp[NP + i]);
        float dz = __fsub_rn(cz, sp[2 * NP + i]);
        float ss = __fadd_rn(__fadd_rn(__fmul_rn(dx, dx), __fmul_rn(dy, dy)),
                             __fmul_rn(dz, dz));
        m = fminf(m, ss);
      }
      #pragma unroll
      for (int off = 32; off > 0; off >>= 1)
        m = fminf(m, __shfl_down(m, off, 64));
      int wid = tid >> 6;
      __syncthreads();
      if ((tid & 63) == 0) red[wid] = m;
      __syncthreads();
      if (tid == 0) {
        float mm = fminf(fminf(red[0], red[1]), fminf(red[2], red[3]));
        red[4] = sqrtf(mm);
      }
      __syncthreads();
      float mind = red[4];
      if (mind > 0.4f && k < 100) {
        cx = __fsub_rn(cx, __fmul_rn(0.01f, cx));
        cy = __fsub_rn(cy, __fmul_rn(0.01f, cy));
        cz = __fsub_rn(cz, __fmul_rn(0.01f, cz));
        k++;
      } else {
        break;
      }
    }
    if (tid == 0) {
      cage[(size_t)b * 3 * NV + v]          = cx;
      cage[(size_t)b * 3 * NV + NV + v]     = cy;
      cage[(size_t)b * 3 * NV + 2 * NV + v] = cz;
    }
  } else {
    int idx = blockIdx.x - BB * NV;   // 0..127
    splitk_body(sf, tf, W1, b1, h1, 512, 512, 1, idx & 7, idx >> 3,
                tid, sIn, part);
  }
}

// ---------------- standalone split-K linear (round-3 proven) ----------------
__global__ __launch_bounds__(256) void linear_splitk(
    const float* __restrict__ in0, const float* __restrict__ in1,
    const float* __restrict__ W, const float* __restrict__ bias,
    float* __restrict__ out, int FI, int FO, int relu)
{
  __shared__ float sIn[512];
  __shared__ float part[4][64];
  splitk_body(in0, in1, W, bias, out, FI, FO, relu,
              blockIdx.x, blockIdx.y, threadIdx.x, sIn, part);
}

// ---------------- L4 + cage finalize (round-3 proven) ----------------
__global__ __launch_bounds__(128) void l4_finalize_kernel(
    const float* __restrict__ h3,
    const float* __restrict__ W4, const float* __restrict__ b4,
    const float* __restrict__ cage,
    float* __restrict__ out_io,
    float* __restrict__ cage_t,
    float* __restrict__ ncage_t)
{
  __shared__ float sIn[256];
  int bb = blockIdx.x;
  int tid = threadIdx.x;
  sIn[tid] = h3[(size_t)bb * 256 + tid];
  sIn[tid + 128] = h3[(size_t)bb * 256 + tid + 128];
  __syncthreads();
  if (tid < 126) {
    float acc = b4[tid];
    const float* wp = W4 + tid;
    #pragma unroll 4
    for (int i = 0; i < 256; i++) acc = fmaf(sIn[i], wp[(size_t)i * 126], acc);
    out_io[(size_t)bb * 126 + tid] = acc;
    float c  = cage[(size_t)bb * 126 + tid];
    float nc = c + acc;
    int d = tid / NV, v = tid - d * NV;
    cage_t[(size_t)bb * NV * 3 + v * 3 + d]  = c;
    ncage_t[(size_t)bb * NV * 3 + v * 3 + d] = nc;
  }
}

extern "C" void kernel_launch(void* const* d_in, const int* in_sizes, int n_in,
                              void* d_out, int out_size, void* d_ws, size_t ws_size,
                              hipStream_t stream) {
  (void)in_sizes; (void)n_in; (void)out_size; (void)d_ws; (void)ws_size;
  const float* src   = (const float*)d_in[0];
  const float* sf    = (const float*)d_in[2];
  const float* tf    = (const float*)d_in[3];
  const float* tmpl  = (const float*)d_in[4];
  const int*   faces = (const int*)d_in[5];
  const float* W1 = (const float*)d_in[6];  const float* b1 = (const float*)d_in[7];
  const float* W2 = (const float*)d_in[8];  const float* b2 = (const float*)d_in[9];
  const float* W3 = (const float*)d_in[10]; const float* b3 = (const float*)d_in[11];
  const float* W4 = (const float*)d_in[12]; const float* b4 = (const float*)d_in[13];

  float* out = (float*)d_out;
  float* out_cage_t  = out;                 // (16,42,3)   2016
  float* out_ncage_t = out + 2016;          // (16,42,3)   2016
  float* out_def     = out + 4032;          // (16,3,8192) 393216
  float* out_w       = out + 397248;        // (16,8192,42) 5505024
  float* out_io      = out + 5902272;       // (16,126)    2016

  // scratch carved out of the weights region (fully overwritten by mvc_kernel)
  float* s_cage = out_w;           // 2016
  float* s_h1   = out_w + 2016;    // 8192
  float* s_h2   = out_w + 10208;   // 8192
  float* s_h3   = out_w + 18400;   // 4096

  cage_l1_kernel<<<dim3(BB * NV + 128), dim3(256), 0, stream>>>(
      tmpl, src, sf, tf, W1, b1, s_cage, s_h1);
  linear_splitk<<<dim3(8, BB), dim3(256), 0, stream>>>(s_h1, nullptr, W2, b2, s_h2, 512, 512, 1);
  linear_splitk<<<dim3(4, BB), dim3(256), 0, stream>>>(s_h2, nullptr, W3, b3, s_h3, 512, 256, 1);
  l4_finalize_kernel<<<dim3(BB), dim3(128), 0, stream>>>(
      s_h3, W4, b4, s_cage, out_io, out_cage_t, out_ncage_t);
  mvc_kernel<<<dim3(BB * (NP / PPB)), dim3(128), 0, stream>>>(
      src, out_cage_t, out_ncage_t, faces, out_def, out_w);
}

// Round 17
// 137.044 us; speedup vs baseline: 1.1665x; 1.1665x over previous
//
#include <hip/hip_runtime.h>
#include <math.h>

#define BB 16
#define NP 8192
#define NV 42
#define NF 80
#define FEAT 256
#define PPB 64           // points per block (mvc)
#define NWV 4            // waves per mvc block
#define FPW 20           // faces per wave
#define WJS 65           // padded LDS stride (65%32==1 -> transposed epilogue conflict-free)

__device__ __forceinline__ float rcp_f(float x)  { return __builtin_amdgcn_rcpf(x); }
__device__ __forceinline__ float rsq_f(float x)  { return __builtin_amdgcn_rsqf(x); }
__device__ __forceinline__ float sqrt_f(float x) { return __builtin_amdgcn_sqrtf(x); }

// theta = 2*asin(x), x in [0,1). Branchless, |err|~1e-5. (validated r2-r16)
__device__ __forceinline__ float theta_from_x(float x) {
  bool big = x > 0.5f;
  float z = big ? fmaf(-0.5f, x, 0.5f) : x * x;
  float s = big ? sqrt_f(z) : x;
  float P = fmaf(z, 0.022371875f, 0.030381944f);
  P = fmaf(z, P, 0.044642857f);
  P = fmaf(z, P, 0.075f);
  P = fmaf(z, P, 0.16666667f);
  float r = fmaf(s * z, P, s);
  return big ? fmaf(-4.f, r, 3.14159265358979f) : 2.f * r;
}

// cold path: runtime face recompute, inside-formula accumulate into private region
__device__ __attribute__((noinline)) void inside_face_rt(
    int f0, int f1, int f2, const float4* vpos,
    float qx, float qy, float qz, float* wjh)
{
  float4 v0 = vpos[f0], v1 = vpos[f1], v2 = vpos[f2];
  float a0x = v0.x - qx, a0y = v0.y - qy, a0z = v0.z - qz;
  float a1x = v1.x - qx, a1y = v1.y - qy, a1z = v1.z - qz;
  float a2x = v2.x - qx, a2y = v2.y - qy, a2z = v2.z - qz;
  float ss0 = fmaf(a0x, a0x, fmaf(a0y, a0y, a0z * a0z));
  float ss1 = fmaf(a1x, a1x, fmaf(a1y, a1y, a1z * a1z));
  float ss2 = fmaf(a2x, a2x, fmaf(a2y, a2y, a2z * a2z));
  float i0 = rsq_f(ss0), i1 = rsq_f(ss1), i2 = rsq_f(ss2);
  float d0 = ss0 * i0, d1 = ss1 * i1, d2 = ss2 * i2;
  float u0x = a0x * i0, u0y = a0y * i0, u0z = a0z * i0;
  float u1x = a1x * i1, u1y = a1y * i1, u1z = a1z * i1;
  float u2x = a2x * i2, u2y = a2y * i2, u2z = a2z * i2;
  float ex = u1x - u2x, ey = u1y - u2y, ez = u1z - u2z;
  float x0 = 0.5f * sqrt_f(fmaf(ex, ex, fmaf(ey, ey, ez * ez)));
  ex = u2x - u0x; ey = u2y - u0y; ez = u2z - u0z;
  float x1 = 0.5f * sqrt_f(fmaf(ex, ex, fmaf(ey, ey, ez * ez)));
  ex = u0x - u1x; ey = u0y - u1y; ez = u0z - u1z;
  float x2 = 0.5f * sqrt_f(fmaf(ex, ex, fmaf(ey, ey, ez * ez)));
  if (x0 >= 1.f) x0 = 0.99999f;
  if (x1 >= 1.f) x1 = 0.99999f;
  if (x2 >= 1.f) x2 = 0.99999f;
  float th0 = theta_from_x(x0), th1 = theta_from_x(x1), th2 = theta_from_x(x2);
  float hh = 0.5f * ((th0 + th1) + th2);
  if (3.14159265358979f - hh < 1e-4f) {
    float cx0 = sqrt_f(fmaxf(fmaf(-x0, x0, 1.f), 0.f));
    float cx1 = sqrt_f(fmaxf(fmaf(-x1, x1, 1.f), 0.f));
    float cx2 = sqrt_f(fmaxf(fmaf(-x2, x2, 1.f), 0.f));
    wjh[f0 * WJS] += (2.f * (x0 * cx0) * d2) * d1;
    wjh[f1 * WJS] += (2.f * (x1 * cx1) * d0) * d2;
    wjh[f2 * WJS] += (2.f * (x2 * cx2) * d1) * d0;
  }
}

// ---------------- Kernel D: MVC weights + deformed ----------------
// 256 threads = 4 waves; block owns 64 points (p = tid&63). Wave q computes
// faces [20q,20q+20) into its own private stride-65 region (no atomics).
// Same total instructions as r15, 2x waves -> better stall overlap.
__global__ __launch_bounds__(256) void mvc_kernel(
    const float* __restrict__ src,      // (B,3,N)
    const float* __restrict__ cage_t,   // (B,42,3)
    const float* __restrict__ ncage_t,  // (B,42,3)
    const int* __restrict__ faces,      // (80,3)
    float* __restrict__ out_def,        // (B,3,N)
    float* __restrict__ out_w)          // (B,N,42)
{
  __shared__ float4 vpos[NV];
  __shared__ float4 npos[NV];
  __shared__ int fidp[NF];
  __shared__ float wj[NWV * NV * WJS];
  __shared__ unsigned long long closeM1[PPB];
  __shared__ unsigned char insideF[NWV][PPB];

  const float PI_F = 3.14159265358979323846f;
  int tid = threadIdx.x;
  int p   = tid & (PPB - 1);
  int q   = tid >> 6;
  int b    = blockIdx.x / (NP / PPB);
  int pblk = blockIdx.x % (NP / PPB);
  int gp   = pblk * PPB + p;

  if (tid < NV) {
    const float* cp = cage_t + (size_t)b * NV * 3 + tid * 3;
    vpos[tid] = make_float4(cp[0], cp[1], cp[2], 0.f);
    const float* np_ = ncage_t + (size_t)b * NV * 3 + tid * 3;
    npos[tid] = make_float4(np_[0], np_[1], np_[2], 0.f);
  }
  if (tid < NF) {
    int f0 = faces[3 * tid], f1 = faces[3 * tid + 1], f2 = faces[3 * tid + 2];
    fidp[tid] = f0 | (f1 << 6) | (f2 << 12);
  }
  for (int i = tid; i < NWV * NV * WJS; i += 256) wj[i] = 0.f;
  __syncthreads();

  float qx = src[(size_t)b * 3 * NP + gp];
  float qy = src[(size_t)b * 3 * NP + NP + gp];
  float qz = src[(size_t)b * 3 * NP + 2 * NP + gp];

  // close-mask hoist (r12-validated): per-vertex distance check; all waves
  // compute identical masks, wave0 stores.
  {
    unsigned long long cl = 0ull;
    for (int c = 0; c < NV; c++) {
      float4 v = vpos[c];
      float ax = v.x - qx, ay = v.y - qy, az = v.z - qz;
      float ss = fmaf(ax, ax, fmaf(ay, ay, az * az));
      if (ss < 1e-16f) cl |= (1ull << c);   // d<1e-8 <=> ss<1e-16
    }
    if (q == 0) closeM1[p] = cl;
  }

  int anyInside = 0;
  float* wjh = wj + q * (NV * WJS) + p;

  // one face, r8-validated math
  auto face_eval = [&](int i, int& f0, int& f1, int& f2,
                       float& w0, float& w1, float& w2) {
    int pk = fidp[i];
    f0 = pk & 63; f1 = (pk >> 6) & 63; f2 = pk >> 12;
    float4 v0 = vpos[f0], v1 = vpos[f1], v2 = vpos[f2];
    float a0x = v0.x - qx, a0y = v0.y - qy, a0z = v0.z - qz;
    float a1x = v1.x - qx, a1y = v1.y - qy, a1z = v1.z - qz;
    float a2x = v2.x - qx, a2y = v2.y - qy, a2z = v2.z - qz;
    float ss0 = fmaf(a0x, a0x, fmaf(a0y, a0y, a0z * a0z));
    float ss1 = fmaf(a1x, a1x, fmaf(a1y, a1y, a1z * a1z));
    float ss2 = fmaf(a2x, a2x, fmaf(a2y, a2y, a2z * a2z));
    float i0 = rsq_f(ss0), i1 = rsq_f(ss1), i2 = rsq_f(ss2);
    float d0 = ss0 * i0, d1 = ss1 * i1, d2 = ss2 * i2;
    float u0x = a0x * i0, u0y = a0y * i0, u0z = a0z * i0;
    float u1x = a1x * i1, u1y = a1y * i1, u1z = a1z * i1;
    float u2x = a2x * i2, u2y = a2y * i2, u2z = a2z * i2;
    // chord half-lengths via EDGE SUBTRACTION (r7 lesson: never 1-u.u')
    float ex = u1x - u2x, ey = u1y - u2y, ez = u1z - u2z;
    float x0 = 0.5f * sqrt_f(fmaf(ex, ex, fmaf(ey, ey, ez * ez)));
    ex = u2x - u0x; ey = u2y - u0y; ez = u2z - u0z;
    float x1 = 0.5f * sqrt_f(fmaf(ex, ex, fmaf(ey, ey, ez * ez)));
    ex = u0x - u1x; ey = u0y - u1y; ez = u0z - u1z;
    float x2 = 0.5f * sqrt_f(fmaf(ex, ex, fmaf(ey, ey, ez * ez)));
    if (x0 >= 1.f) x0 = 0.99999f;     // reference clamp l>=2 -> 1.99998
    if (x1 >= 1.f) x1 = 0.99999f;
    if (x2 >= 1.f) x2 = 0.99999f;
    float cx0 = sqrt_f(fmaxf(fmaf(-x0, x0, 1.f), 0.f));
    float cx1 = sqrt_f(fmaxf(fmaf(-x1, x1, 1.f), 0.f));
    float cx2 = sqrt_f(fmaxf(fmaf(-x2, x2, 1.f), 0.f));
    float th0 = theta_from_x(x0);
    float th1 = theta_from_x(x1);
    float th2 = theta_from_x(x2);
    float hh = 0.5f * ((th0 + th1) + th2);
    if (PI_F - hh < 1e-4f) anyInside = 1;
    float t0 = x0 * cx0, t1 = x1 * cx1, t2 = x2 * cx2;
    float st0 = t0 + t0, st1 = t1 + t1, st2 = t2 + t2;   // sin(theta_i)
    float A1 = x0 * (cx1 * cx2);
    float A2 = x1 * (cx0 * cx2);
    float A3 = x2 * (cx0 * cx1);
    float A4 = x0 * (x1 * x2);
    float sh  = ((A1 + A2) + A3) - A4;     // sin(h)
    float sm0 = ((-A1 + A2) + A3) + A4;    // sin(h-th0)
    float sm1 = ((A1 - A2) + A3) + A4;
    float sm2 = ((A1 + A2) - A3) + A4;
    float twosh = sh + sh;
    float c0 = fmaf(twosh * sm0, rcp_f(st1 * st2), -1.f);
    float c1 = fmaf(twosh * sm1, rcp_f(st2 * st0), -1.f);
    float c2 = fmaf(twosh * sm2, rcp_f(st0 * st1), -1.f);
    c0 = fminf(fmaxf(c0, -0.99999f), 0.99999f);
    c1 = fminf(fmaxf(c1, -0.99999f), 0.99999f);
    c2 = fminf(fmaxf(c2, -0.99999f), 0.99999f);
    float det = u0x * fmaf(u1y, u2z, -(u1z * u2y))
              - u0y * fmaf(u1x, u2z, -(u1z * u2x))
              + u0z * fmaf(u1x, u2y, -(u1y * u2x));
    float sg = (det > 0.f) ? 1.f : ((det < 0.f) ? -1.f : 0.f);
    float sn0 = sg * sqrt_f(fmaf(-c0, c0, 1.f));
    float sn1 = sg * sqrt_f(fmaf(-c1, c1, 1.f));
    float sn2 = sg * sqrt_f(fmaf(-c2, c2, 1.f));
    w0 = fmaf(-c2, th1, fmaf(-c1, th2, th0)) * rcp_f((d0 * st1) * sn2);
    w1 = fmaf(-c0, th2, fmaf(-c2, th0, th1)) * rcp_f((d1 * st2) * sn0);
    w2 = fmaf(-c1, th0, fmaf(-c0, th1, th2)) * rcp_f((d2 * st0) * sn1);
  };

  #pragma unroll 1
  for (int i = q * FPW; i < q * FPW + FPW; i++) {
    int f0, f1, f2;
    float w0, w1, w2;
    face_eval(i, f0, f1, f2, w0, w1, w2);
    wjh[f0 * WJS] += w0;      // private region: no atomics
    wjh[f1 * WJS] += w1;
    wjh[f2 * WJS] += w2;
  }

  insideF[q][p] = (unsigned char)anyInside;
  __syncthreads();

  int mIn = insideF[0][p] | insideF[1][p] | insideF[2][p] | insideF[3][p];
  unsigned long long mCl = closeM1[p];

  if (mIn) {   // cold: exact `where(inside, ...)` semantics
    for (int c = 0; c < NV; c++) wjh[c * WJS] = 0.f;
    #pragma unroll 1
    for (int i = q * FPW; i < q * FPW + FPW; i++) {
      int pk = fidp[i];
      inside_face_rt(pk & 63, (pk >> 6) & 63, pk >> 12, vpos, qx, qy, qz, wjh);
    }
  }
  __syncthreads();

  if (tid < PPB) {
    float sum = 0.f;
    for (int c = 0; c < NV; c++) {
      float w = (wj[c * WJS + p] + wj[(NV + c) * WJS + p]) +
                (wj[(2 * NV + c) * WJS + p] + wj[(3 * NV + c) * WJS + p]);
      if (mCl) w = ((mCl >> c) & 1ull) ? 1.f : 0.f;
      wj[c * WJS + p] = w;
      sum += w;
    }
    if (sum == 0.f) sum = 1.f;
    float inv = rcp_f(sum);
    float ax = 0.f, ay = 0.f, az = 0.f;
    for (int c = 0; c < NV; c++) {
      float w = wj[c * WJS + p] * inv;
      wj[c * WJS + p] = w;
      float4 n = npos[c];
      ax = fmaf(w, n.x, ax);
      ay = fmaf(w, n.y, ay);
      az = fmaf(w, n.z, az);
    }
    out_def[(size_t)b * 3 * NP + gp]          = ax;
    out_def[(size_t)b * 3 * NP + NP + gp]     = ay;
    out_def[(size_t)b * 3 * NP + 2 * NP + gp] = az;
  }
  __syncthreads();

  // coalesced weight write; stride 65 -> conflict-free transposed read
  float* wbase = out_w + ((size_t)b * NP + pblk * PPB) * NV;
  for (int idx = tid; idx < PPB * NV; idx += 256) {
    int pp = idx / NV;
    int c  = idx - pp * NV;
    wbase[idx] = wj[c * WJS + pp];
  }
}

// ---------------- shared split-K linear body (round-3 proven) ----------------
__device__ __forceinline__ void splitk_body(
    const float* in0, const float* in1,
    const float* W, const float* bias, float* out,
    int FI, int FO, int relu, int ox, int bb, int tid,
    float* sIn, float (*part)[64])
{
  for (int i = tid; i < FI; i += 256) {
    float v;
    if (in1) v = (i < FEAT) ? in0[(size_t)bb * FEAT + i]
                            : in1[(size_t)bb * FEAT + i - FEAT];
    else     v = in0[(size_t)bb * FI + i];
    sIn[i] = v;
  }
  __syncthreads();
  int o = ox * 64 + (tid & 63);
  int kk = tid >> 6;
  int seg = FI >> 2;
  float acc = 0.f;
  const float* wp = W + o;
  #pragma unroll 4
  for (int i = kk * seg; i < (kk + 1) * seg; i++)
    acc = fmaf(sIn[i], wp[(size_t)i * FO], acc);
  part[kk][tid & 63] = acc;
  __syncthreads();
  if (tid < 64) {
    float r = ((part[0][tid] + part[1][tid]) + (part[2][tid] + part[3][tid]))
              + bias[o];
    out[(size_t)bb * FO + o] = relu ? fmaxf(r, 0.f) : r;
  }
}

// ---------------- Kernel A: cage_opt (blocks<672) + L1 split-K (672..799) ----
__global__ __launch_bounds__(256) void cage_l1_kernel(
    const float* __restrict__ tmpl, const float* __restrict__ src,
    const float* __restrict__ sf, const float* __restrict__ tf,
    const float* __restrict__ W1, const float* __restrict__ b1,
    float* __restrict__ cage, float* __restrict__ h1)
{
  __shared__ float red[8];
  __shared__ float sIn[512];
  __shared__ float part[4][64];
  int tid = threadIdx.x;

  if (blockIdx.x < BB * NV) {
    int b = blockIdx.x / NV;
    int v = blockIdx.x % NV;
    const float* sp = src + (size_t)b * 3 * NP;
    float cx = tmpl[v], cy = tmpl[NV + v], cz = tmpl[2 * NV + v];
    int k = 0;
    while (true) {
      float m = 3.4e38f;
      for (int i = tid; i < NP; i += 256) {
        float dx = __fsub_rn(cx, sp[i]);
        float dy = __fsub_rn(cy, sp[NP + i]);
        float dz = __fsub_rn(cz, sp[2 * NP + i]);
        float ss = __fadd_rn(__fadd_rn(__fmul_rn(dx, dx), __fmul_rn(dy, dy)),
                             __fmul_rn(dz, dz));
        m = fminf(m, ss);
      }
      #pragma unroll
      for (int off = 32; off > 0; off >>= 1)
        m = fminf(m, __shfl_down(m, off, 64));
      int wid = tid >> 6;
      __syncthreads();
      if ((tid & 63) == 0) red[wid] = m;
      __syncthreads();
      if (tid == 0) {
        float mm = fminf(fminf(red[0], red[1]), fminf(red[2], red[3]));
        red[4] = sqrtf(mm);
      }
      __syncthreads();
      float mind = red[4];
      if (mind > 0.4f && k < 100) {
        cx = __fsub_rn(cx, __fmul_rn(0.01f, cx));
        cy = __fsub_rn(cy, __fmul_rn(0.01f, cy));
        cz = __fsub_rn(cz, __fmul_rn(0.01f, cz));
        k++;
      } else {
        break;
      }
    }
    if (tid == 0) {
      cage[(size_t)b * 3 * NV + v]          = cx;
      cage[(size_t)b * 3 * NV + NV + v]     = cy;
      cage[(size_t)b * 3 * NV + 2 * NV + v] = cz;
    }
  } else {
    int idx = blockIdx.x - BB * NV;   // 0..127
    splitk_body(sf, tf, W1, b1, h1, 512, 512, 1, idx & 7, idx >> 3,
                tid, sIn, part);
  }
}

// ---------------- standalone split-K linear (round-3 proven) ----------------
__global__ __launch_bounds__(256) void linear_splitk(
    const float* __restrict__ in0, const float* __restrict__ in1,
    const float* __restrict__ W, const float* __restrict__ bias,
    float* __restrict__ out, int FI, int FO, int relu)
{
  __shared__ float sIn[512];
  __shared__ float part[4][64];
  splitk_body(in0, in1, W, bias, out, FI, FO, relu,
              blockIdx.x, blockIdx.y, threadIdx.x, sIn, part);
}

// ---------------- L4 + cage finalize (round-3 proven) ----------------
__global__ __launch_bounds__(128) void l4_finalize_kernel(
    const float* __restrict__ h3,
    const float* __restrict__ W4, const float* __restrict__ b4,
    const float* __restrict__ cage,
    float* __restrict__ out_io,
    float* __restrict__ cage_t,
    float* __restrict__ ncage_t)
{
  __shared__ float sIn[256];
  int bb = blockIdx.x;
  int tid = threadIdx.x;
  sIn[tid] = h3[(size_t)bb * 256 + tid];
  sIn[tid + 128] = h3[(size_t)bb * 256 + tid + 128];
  __syncthreads();
  if (tid < 126) {
    float acc = b4[tid];
    const float* wp = W4 + tid;
    #pragma unroll 4
    for (int i = 0; i < 256; i++) acc = fmaf(sIn[i], wp[(size_t)i * 126], acc);
    out_io[(size_t)bb * 126 + tid] = acc;
    float c  = cage[(size_t)bb * 126 + tid];
    float nc = c + acc;
    int d = tid / NV, v = tid - d * NV;
    cage_t[(size_t)bb * NV * 3 + v * 3 + d]  = c;
    ncage_t[(size_t)bb * NV * 3 + v * 3 + d] = nc;
  }
}

extern "C" void kernel_launch(void* const* d_in, const int* in_sizes, int n_in,
                              void* d_out, int out_size, void* d_ws, size_t ws_size,
                              hipStream_t stream) {
  (void)in_sizes; (void)n_in; (void)out_size; (void)d_ws; (void)ws_size;
  const float* src   = (const float*)d_in[0];
  const float* sf    = (const float*)d_in[2];
  const float* tf    = (const float*)d_in[3];
  const float* tmpl  = (const float*)d_in[4];
  const int*   faces = (const int*)d_in[5];
  const float* W1 = (const float*)d_in[6];  const float* b1 = (const float*)d_in[7];
  const float* W2 = (const float*)d_in[8];  const float* b2 = (const float*)d_in[9];
  const float* W3 = (const float*)d_in[10]; const float* b3 = (const float*)d_in[11];
  const float* W4 = (const float*)d_in[12]; const float* b4 = (const float*)d_in[13];

  float* out = (float*)d_out;
  float* out_cage_t  = out;                 // (16,42,3)   2016
  float* out_ncage_t = out + 2016;          // (16,42,3)   2016
  float* out_def     = out + 4032;          // (16,3,8192) 393216
  float* out_w       = out + 397248;        // (16,8192,42) 5505024
  float* out_io      = out + 5902272;       // (16,126)    2016

  // scratch carved out of the weights region (fully overwritten by mvc_kernel)
  float* s_cage = out_w;           // 2016
  float* s_h1   = out_w + 2016;    // 8192
  float* s_h2   = out_w + 10208;   // 8192
  float* s_h3   = out_w + 18400;   // 4096

  cage_l1_kernel<<<dim3(BB * NV + 128), dim3(256), 0, stream>>>(
      tmpl, src, sf, tf, W1, b1, s_cage, s_h1);
  linear_splitk<<<dim3(8, BB), dim3(256), 0, stream>>>(s_h1, nullptr, W2, b2, s_h2, 512, 512, 1);
  linear_splitk<<<dim3(4, BB), dim3(256), 0, stream>>>(s_h2, nullptr, W3, b3, s_h3, 512, 256, 1);
  l4_finalize_kernel<<<dim3(BB), dim3(128), 0, stream>>>(
      s_h3, W4, b4, s_cage, out_io, out_cage_t, out_ncage_t);
  mvc_kernel<<<dim3(BB * (NP / PPB)), dim3(256), 0, stream>>>(
      src, out_cage_t, out_ncage_t, faces, out_def, out_w);
}

// Round 18
// 136.586 us; speedup vs baseline: 1.1704x; 1.0034x over previous
//
#include <hip/hip_runtime.h>
#include <math.h>

#define BB 16
#define NP 8192
#define NV 42
#define NF 80
#define FEAT 256
#define PPB 64           // points per block (mvc)
#define NWV 4            // waves per mvc block (r17-proven optimum)
#define FPW 20           // faces per wave
#define WJS 65           // padded LDS stride (65%32==1 -> transposed epilogue conflict-free)

__device__ __forceinline__ float rcp_f(float x)  { return __builtin_amdgcn_rcpf(x); }
__device__ __forceinline__ float rsq_f(float x)  { return __builtin_amdgcn_rsqf(x); }
__device__ __forceinline__ float sqrt_f(float x) { return __builtin_amdgcn_sqrtf(x); }

// theta = 2*asin(x), x in [0,1). Branchless, |err|~1e-5. (validated r2-r17)
__device__ __forceinline__ float theta_from_x(float x) {
  bool big = x > 0.5f;
  float z = big ? fmaf(-0.5f, x, 0.5f) : x * x;
  float s = big ? sqrt_f(z) : x;
  float P = fmaf(z, 0.022371875f, 0.030381944f);
  P = fmaf(z, P, 0.044642857f);
  P = fmaf(z, P, 0.075f);
  P = fmaf(z, P, 0.16666667f);
  float r = fmaf(s * z, P, s);
  return big ? fmaf(-4.f, r, 3.14159265358979f) : 2.f * r;
}

// cold path: runtime face recompute, inside-formula accumulate into private region
__device__ __attribute__((noinline)) void inside_face_rt(
    int f0, int f1, int f2, const float4* vpos,
    float qx, float qy, float qz, float* wjh)
{
  float4 v0 = vpos[f0], v1 = vpos[f1], v2 = vpos[f2];
  float a0x = v0.x - qx, a0y = v0.y - qy, a0z = v0.z - qz;
  float a1x = v1.x - qx, a1y = v1.y - qy, a1z = v1.z - qz;
  float a2x = v2.x - qx, a2y = v2.y - qy, a2z = v2.z - qz;
  float ss0 = fmaf(a0x, a0x, fmaf(a0y, a0y, a0z * a0z));
  float ss1 = fmaf(a1x, a1x, fmaf(a1y, a1y, a1z * a1z));
  float ss2 = fmaf(a2x, a2x, fmaf(a2y, a2y, a2z * a2z));
  float i0 = rsq_f(ss0), i1 = rsq_f(ss1), i2 = rsq_f(ss2);
  float d0 = ss0 * i0, d1 = ss1 * i1, d2 = ss2 * i2;
  float u0x = a0x * i0, u0y = a0y * i0, u0z = a0z * i0;
  float u1x = a1x * i1, u1y = a1y * i1, u1z = a1z * i1;
  float u2x = a2x * i2, u2y = a2y * i2, u2z = a2z * i2;
  float ex = u1x - u2x, ey = u1y - u2y, ez = u1z - u2z;
  float x0 = 0.5f * sqrt_f(fmaf(ex, ex, fmaf(ey, ey, ez * ez)));
  ex = u2x - u0x; ey = u2y - u0y; ez = u2z - u0z;
  float x1 = 0.5f * sqrt_f(fmaf(ex, ex, fmaf(ey, ey, ez * ez)));
  ex = u0x - u1x; ey = u0y - u1y; ez = u0z - u1z;
  float x2 = 0.5f * sqrt_f(fmaf(ex, ex, fmaf(ey, ey, ez * ez)));
  if (x0 >= 1.f) x0 = 0.99999f;
  if (x1 >= 1.f) x1 = 0.99999f;
  if (x2 >= 1.f) x2 = 0.99999f;
  float th0 = theta_from_x(x0), th1 = theta_from_x(x1), th2 = theta_from_x(x2);
  float hh = 0.5f * ((th0 + th1) + th2);
  if (3.14159265358979f - hh < 1e-4f) {
    float cx0 = sqrt_f(fmaxf(fmaf(-x0, x0, 1.f), 0.f));
    float cx1 = sqrt_f(fmaxf(fmaf(-x1, x1, 1.f), 0.f));
    float cx2 = sqrt_f(fmaxf(fmaf(-x2, x2, 1.f), 0.f));
    wjh[f0 * WJS] += (2.f * (x0 * cx0) * d2) * d1;
    wjh[f1 * WJS] += (2.f * (x1 * cx1) * d0) * d2;
    wjh[f2 * WJS] += (2.f * (x2 * cx2) * d1) * d0;
  }
}

// ---------------- Kernel D: MVC weights + deformed ----------------
// 256 threads = 4 waves; block owns 64 points (p = tid&63). Wave q computes
// faces [20q,20q+20) into its own private stride-65 region (no atomics).
__global__ __launch_bounds__(256, 3) void mvc_kernel(
    const float* __restrict__ src,      // (B,3,N)
    const float* __restrict__ cage_t,   // (B,42,3)
    const float* __restrict__ ncage_t,  // (B,42,3)
    const int* __restrict__ faces,      // (80,3)
    float* __restrict__ out_def,        // (B,3,N)
    float* __restrict__ out_w)          // (B,N,42)
{
  __shared__ float4 vpos[NV];
  __shared__ float4 npos[NV];
  __shared__ int fidp[NF];
  __shared__ float wj[NWV * NV * WJS];
  __shared__ unsigned long long closeM1[PPB];
  __shared__ unsigned char insideF[NWV][PPB];

  const float PI_F = 3.14159265358979323846f;
  int tid = threadIdx.x;
  int p   = tid & (PPB - 1);
  int q   = tid >> 6;
  int b    = blockIdx.x / (NP / PPB);
  int pblk = blockIdx.x % (NP / PPB);
  int gp   = pblk * PPB + p;

  if (tid < NV) {
    const float* cp = cage_t + (size_t)b * NV * 3 + tid * 3;
    vpos[tid] = make_float4(cp[0], cp[1], cp[2], 0.f);
    const float* np_ = ncage_t + (size_t)b * NV * 3 + tid * 3;
    npos[tid] = make_float4(np_[0], np_[1], np_[2], 0.f);
  }
  if (tid < NF) {
    int f0 = faces[3 * tid], f1 = faces[3 * tid + 1], f2 = faces[3 * tid + 2];
    fidp[tid] = f0 | (f1 << 6) | (f2 << 12);
  }
  for (int i = tid; i < NWV * NV * WJS; i += 256) wj[i] = 0.f;
  __syncthreads();

  float qx = src[(size_t)b * 3 * NP + gp];
  float qy = src[(size_t)b * 3 * NP + NP + gp];
  float qz = src[(size_t)b * 3 * NP + 2 * NP + gp];

  // close-mask hoist (r12-validated): per-vertex distance check; all waves
  // compute identical masks, wave0 stores.
  {
    unsigned long long cl = 0ull;
    for (int c = 0; c < NV; c++) {
      float4 v = vpos[c];
      float ax = v.x - qx, ay = v.y - qy, az = v.z - qz;
      float ss = fmaf(ax, ax, fmaf(ay, ay, az * az));
      if (ss < 1e-16f) cl |= (1ull << c);   // d<1e-8 <=> ss<1e-16
    }
    if (q == 0) closeM1[p] = cl;
  }

  int anyInside = 0;
  float* wjh = wj + q * (NV * WJS) + p;

  // one face, r8-validated math
  auto face_eval = [&](int i, int& f0, int& f1, int& f2,
                       float& w0, float& w1, float& w2) {
    int pk = fidp[i];
    f0 = pk & 63; f1 = (pk >> 6) & 63; f2 = pk >> 12;
    float4 v0 = vpos[f0], v1 = vpos[f1], v2 = vpos[f2];
    float a0x = v0.x - qx, a0y = v0.y - qy, a0z = v0.z - qz;
    float a1x = v1.x - qx, a1y = v1.y - qy, a1z = v1.z - qz;
    float a2x = v2.x - qx, a2y = v2.y - qy, a2z = v2.z - qz;
    float ss0 = fmaf(a0x, a0x, fmaf(a0y, a0y, a0z * a0z));
    float ss1 = fmaf(a1x, a1x, fmaf(a1y, a1y, a1z * a1z));
    float ss2 = fmaf(a2x, a2x, fmaf(a2y, a2y, a2z * a2z));
    float i0 = rsq_f(ss0), i1 = rsq_f(ss1), i2 = rsq_f(ss2);
    float d0 = ss0 * i0, d1 = ss1 * i1, d2 = ss2 * i2;
    float u0x = a0x * i0, u0y = a0y * i0, u0z = a0z * i0;
    float u1x = a1x * i1, u1y = a1y * i1, u1z = a1z * i1;
    float u2x = a2x * i2, u2y = a2y * i2, u2z = a2z * i2;
    // chord half-lengths via EDGE SUBTRACTION (r7 lesson: never 1-u.u')
    float ex = u1x - u2x, ey = u1y - u2y, ez = u1z - u2z;
    float x0 = 0.5f * sqrt_f(fmaf(ex, ex, fmaf(ey, ey, ez * ez)));
    ex = u2x - u0x; ey = u2y - u0y; ez = u2z - u0z;
    float x1 = 0.5f * sqrt_f(fmaf(ex, ex, fmaf(ey, ey, ez * ez)));
    ex = u0x - u1x; ey = u0y - u1y; ez = u0z - u1z;
    float x2 = 0.5f * sqrt_f(fmaf(ex, ex, fmaf(ey, ey, ez * ez)));
    if (x0 >= 1.f) x0 = 0.99999f;     // reference clamp l>=2 -> 1.99998
    if (x1 >= 1.f) x1 = 0.99999f;
    if (x2 >= 1.f) x2 = 0.99999f;
    float cx0 = sqrt_f(fmaxf(fmaf(-x0, x0, 1.f), 0.f));
    float cx1 = sqrt_f(fmaxf(fmaf(-x1, x1, 1.f), 0.f));
    float cx2 = sqrt_f(fmaxf(fmaf(-x2, x2, 1.f), 0.f));
    float th0 = theta_from_x(x0);
    float th1 = theta_from_x(x1);
    float th2 = theta_from_x(x2);
    float hh = 0.5f * ((th0 + th1) + th2);
    if (PI_F - hh < 1e-4f) anyInside = 1;
    float t0 = x0 * cx0, t1 = x1 * cx1, t2 = x2 * cx2;
    float st0 = t0 + t0, st1 = t1 + t1, st2 = t2 + t2;   // sin(theta_i)
    float A1 = x0 * (cx1 * cx2);
    float A2 = x1 * (cx0 * cx2);
    float A3 = x2 * (cx0 * cx1);
    float A4 = x0 * (x1 * x2);
    float sh  = ((A1 + A2) + A3) - A4;     // sin(h)
    float sm0 = ((-A1 + A2) + A3) + A4;    // sin(h-th0)
    float sm1 = ((A1 - A2) + A3) + A4;
    float sm2 = ((A1 + A2) - A3) + A4;
    float twosh = sh + sh;
    float c0 = fmaf(twosh * sm0, rcp_f(st1 * st2), -1.f);
    float c1 = fmaf(twosh * sm1, rcp_f(st2 * st0), -1.f);
    float c2 = fmaf(twosh * sm2, rcp_f(st0 * st1), -1.f);
    c0 = fminf(fmaxf(c0, -0.99999f), 0.99999f);
    c1 = fminf(fmaxf(c1, -0.99999f), 0.99999f);
    c2 = fminf(fmaxf(c2, -0.99999f), 0.99999f);
    float det = u0x * fmaf(u1y, u2z, -(u1z * u2y))
              - u0y * fmaf(u1x, u2z, -(u1z * u2x))
              + u0z * fmaf(u1x, u2y, -(u1y * u2x));
    float sg = (det > 0.f) ? 1.f : ((det < 0.f) ? -1.f : 0.f);
    float sn0 = sg * sqrt_f(fmaf(-c0, c0, 1.f));
    float sn1 = sg * sqrt_f(fmaf(-c1, c1, 1.f));
    float sn2 = sg * sqrt_f(fmaf(-c2, c2, 1.f));
    w0 = fmaf(-c2, th1, fmaf(-c1, th2, th0)) * rcp_f((d0 * st1) * sn2);
    w1 = fmaf(-c0, th2, fmaf(-c2, th0, th1)) * rcp_f((d1 * st2) * sn0);
    w2 = fmaf(-c1, th0, fmaf(-c0, th1, th2)) * rcp_f((d2 * st0) * sn1);
  };

  #pragma unroll 2
  for (int i = q * FPW; i < q * FPW + FPW; i++) {
    int f0, f1, f2;
    float w0, w1, w2;
    face_eval(i, f0, f1, f2, w0, w1, w2);
    wjh[f0 * WJS] += w0;      // private region: no atomics
    wjh[f1 * WJS] += w1;
    wjh[f2 * WJS] += w2;
  }

  insideF[q][p] = (unsigned char)anyInside;
  __syncthreads();

  int mIn = insideF[0][p] | insideF[1][p] | insideF[2][p] | insideF[3][p];
  unsigned long long mCl = closeM1[p];

  if (mIn) {   // cold: exact `where(inside, ...)` semantics
    for (int c = 0; c < NV; c++) wjh[c * WJS] = 0.f;
    #pragma unroll 1
    for (int i = q * FPW; i < q * FPW + FPW; i++) {
      int pk = fidp[i];
      inside_face_rt(pk & 63, (pk >> 6) & 63, pk >> 12, vpos, qx, qy, qz, wjh);
    }
  }
  __syncthreads();

  if (tid < PPB) {
    float sum = 0.f;
    for (int c = 0; c < NV; c++) {
      float w = (wj[c * WJS + p] + wj[(NV + c) * WJS + p]) +
                (wj[(2 * NV + c) * WJS + p] + wj[(3 * NV + c) * WJS + p]);
      if (mCl) w = ((mCl >> c) & 1ull) ? 1.f : 0.f;
      wj[c * WJS + p] = w;
      sum += w;
    }
    if (sum == 0.f) sum = 1.f;
    float inv = rcp_f(sum);
    float ax = 0.f, ay = 0.f, az = 0.f;
    for (int c = 0; c < NV; c++) {
      float w = wj[c * WJS + p] * inv;
      wj[c * WJS + p] = w;
      float4 n = npos[c];
      ax = fmaf(w, n.x, ax);
      ay = fmaf(w, n.y, ay);
      az = fmaf(w, n.z, az);
    }
    out_def[(size_t)b * 3 * NP + gp]          = ax;
    out_def[(size_t)b * 3 * NP + NP + gp]     = ay;
    out_def[(size_t)b * 3 * NP + 2 * NP + gp] = az;
  }
  __syncthreads();

  // coalesced weight write; stride 65 -> conflict-free transposed read.
  // incremental pp/c counters (no integer div/mod in the loop).
  {
    float* wbase = out_w + ((size_t)b * NP + pblk * PPB) * NV;
    int pp = tid / NV;
    int c  = tid - pp * NV;
    for (int idx = tid; idx < PPB * NV; idx += 256) {
      wbase[idx] = wj[c * WJS + pp];
      c += 256 - 6 * NV;          // 256 = 6*42 + 4
      pp += 6;
      if (c >= NV) { c -= NV; pp++; }
    }
  }
}

// ---------------- shared split-K linear body (round-3 proven) ----------------
__device__ __forceinline__ void splitk_body(
    const float* in0, const float* in1,
    const float* W, const float* bias, float* out,
    int FI, int FO, int relu, int ox, int bb, int tid,
    float* sIn, float (*part)[64])
{
  for (int i = tid; i < FI; i += 256) {
    float v;
    if (in1) v = (i < FEAT) ? in0[(size_t)bb * FEAT + i]
                            : in1[(size_t)bb * FEAT + i - FEAT];
    else     v = in0[(size_t)bb * FI + i];
    sIn[i] = v;
  }
  __syncthreads();
  int o = ox * 64 + (tid & 63);
  int kk = tid >> 6;
  int seg = FI >> 2;
  float acc = 0.f;
  const float* wp = W + o;
  #pragma unroll 4
  for (int i = kk * seg; i < (kk + 1) * seg; i++)
    acc = fmaf(sIn[i], wp[(size_t)i * FO], acc);
  part[kk][tid & 63] = acc;
  __syncthreads();
  if (tid < 64) {
    float r = ((part[0][tid] + part[1][tid]) + (part[2][tid] + part[3][tid]))
              + bias[o];
    out[(size_t)bb * FO + o] = relu ? fmaxf(r, 0.f) : r;
  }
}

// ---------------- Kernel A: cage_opt (blocks<672) + L1 split-K (672..799) ----
__global__ __launch_bounds__(256) void cage_l1_kernel(
    const float* __restrict__ tmpl, const float* __restrict__ src,
    const float* __restrict__ sf, const float* __restrict__ tf,
    const float* __restrict__ W1, const float* __restrict__ b1,
    float* __restrict__ cage, float* __restrict__ h1)
{
  __shared__ float red[8];
  __shared__ float sIn[512];
  __shared__ float part[4][64];
  int tid = threadIdx.x;

  if (blockIdx.x < BB * NV) {
    int b = blockIdx.x / NV;
    int v = blockIdx.x % NV;
    const float* sp = src + (size_t)b * 3 * NP;
    float cx = tmpl[v], cy = tmpl[NV + v], cz = tmpl[2 * NV + v];
    int k = 0;
    while (true) {
      float m = 3.4e38f;
      for (int i = tid; i < NP; i += 256) {
        float dx = __fsub_rn(cx, sp[i]);
        float dy = __fsub_rn(cy, sp[NP + i]);
        float dz = __fsub_rn(cz, sp[2 * NP + i]);
        float ss = __fadd_rn(__fadd_rn(__fmul_rn(dx, dx), __fmul_rn(dy, dy)),
                             __fmul_rn(dz, dz));
        m = fminf(m, ss);
      }
      #pragma unroll
      for (int off = 32; off > 0; off >>= 1)
        m = fminf(m, __shfl_down(m, off, 64));
      int wid = tid >> 6;
      __syncthreads();
      if ((tid & 63) == 0) red[wid] = m;
      __syncthreads();
      if (tid == 0) {
        float mm = fminf(fminf(red[0], red[1]), fminf(red[2], red[3]));
        red[4] = sqrtf(mm);
      }
      __syncthreads();
      float mind = red[4];
      if (mind > 0.4f && k < 100) {
        cx = __fsub_rn(cx, __fmul_rn(0.01f, cx));
        cy = __fsub_rn(cy, __fmul_rn(0.01f, cy));
        cz = __fsub_rn(cz, __fmul_rn(0.01f, cz));
        k++;
      } else {
        break;
      }
    }
    if (tid == 0) {
      cage[(size_t)b * 3 * NV + v]          = cx;
      cage[(size_t)b * 3 * NV + NV + v]     = cy;
      cage[(size_t)b * 3 * NV + 2 * NV + v] = cz;
    }
  } else {
    int idx = blockIdx.x - BB * NV;   // 0..127
    splitk_body(sf, tf, W1, b1, h1, 512, 512, 1, idx & 7, idx >> 3,
                tid, sIn, part);
  }
}

// ---------------- standalone split-K linear (round-3 proven) ----------------
__global__ __launch_bounds__(256) void linear_splitk(
    const float* __restrict__ in0, const float* __restrict__ in1,
    const float* __restrict__ W, const float* __restrict__ bias,
    float* __restrict__ out, int FI, int FO, int relu)
{
  __shared__ float sIn[512];
  __shared__ float part[4][64];
  splitk_body(in0, in1, W, bias, out, FI, FO, relu,
              blockIdx.x, blockIdx.y, threadIdx.x, sIn, part);
}

// ---------------- L4 + cage finalize (round-3 proven) ----------------
__global__ __launch_bounds__(128) void l4_finalize_kernel(
    const float* __restrict__ h3,
    const float* __restrict__ W4, const float* __restrict__ b4,
    const float* __restrict__ cage,
    float* __restrict__ out_io,
    float* __restrict__ cage_t,
    float* __restrict__ ncage_t)
{
  __shared__ float sIn[256];
  int bb = blockIdx.x;
  int tid = threadIdx.x;
  sIn[tid] = h3[(size_t)bb * 256 + tid];
  sIn[tid + 128] = h3[(size_t)bb * 256 + tid + 128];
  __syncthreads();
  if (tid < 126) {
    float acc = b4[tid];
    const float* wp = W4 + tid;
    #pragma unroll 4
    for (int i = 0; i < 256; i++) acc = fmaf(sIn[i], wp[(size_t)i * 126], acc);
    out_io[(size_t)bb * 126 + tid] = acc;
    float c  = cage[(size_t)bb * 126 + tid];
    float nc = c + acc;
    int d = tid / NV, v = tid - d * NV;
    cage_t[(size_t)bb * NV * 3 + v * 3 + d]  = c;
    ncage_t[(size_t)bb * NV * 3 + v * 3 + d] = nc;
  }
}

extern "C" void kernel_launch(void* const* d_in, const int* in_sizes, int n_in,
                              void* d_out, int out_size, void* d_ws, size_t ws_size,
                              hipStream_t stream) {
  (void)in_sizes; (void)n_in; (void)out_size; (void)d_ws; (void)ws_size;
  const float* src   = (const float*)d_in[0];
  const float* sf    = (const float*)d_in[2];
  const float* tf    = (const float*)d_in[3];
  const float* tmpl  = (const float*)d_in[4];
  const int*   faces = (const int*)d_in[5];
  const float* W1 = (const float*)d_in[6];  const float* b1 = (const float*)d_in[7];
  const float* W2 = (const float*)d_in[8];  const float* b2 = (const float*)d_in[9];
  const float* W3 = (const float*)d_in[10]; const float* b3 = (const float*)d_in[11];
  const float* W4 = (const float*)d_in[12]; const float* b4 = (const float*)d_in[13];

  float* out = (float*)d_out;
  float* out_cage_t  = out;                 // (16,42,3)   2016
  float* out_ncage_t = out + 2016;          // (16,42,3)   2016
  float* out_def     = out + 4032;          // (16,3,8192) 393216
  float* out_w       = out + 397248;        // (16,8192,42) 5505024
  float* out_io      = out + 5902272;       // (16,126)    2016

  // scratch carved out of the weights region (fully overwritten by mvc_kernel)
  float* s_cage = out_w;           // 2016
  float* s_h1   = out_w + 2016;    // 8192
  float* s_h2   = out_w + 10208;   // 8192
  float* s_h3   = out_w + 18400;   // 4096

  cage_l1_kernel<<<dim3(BB * NV + 128), dim3(256), 0, stream>>>(
      tmpl, src, sf, tf, W1, b1, s_cage, s_h1);
  linear_splitk<<<dim3(8, BB), dim3(256), 0, stream>>>(s_h1, nullptr, W2, b2, s_h2, 512, 512, 1);
  linear_splitk<<<dim3(4, BB), dim3(256), 0, stream>>>(s_h2, nullptr, W3, b3, s_h3, 512, 256, 1);
  l4_finalize_kernel<<<dim3(BB), dim3(128), 0, stream>>>(
      s_h3, W4, b4, s_cage, out_io, out_cage_t, out_ncage_t);
  mvc_kernel<<<dim3(BB * (NP / PPB)), dim3(256), 0, stream>>>(
      src, out_cage_t, out_ncage_t, faces, out_def, out_w);
}